// Round 1
// baseline (980.456 us; speedup 1.0000x reference)
//
#include <hip/hip_runtime.h>

// GQA group-attention: q/k/v GEMMs (bf16 MFMA) + per-token 16x16 group attention.
// R0: correctness-first with m97-style GEMM structure (128x128 tile, BK=32,
// global_load_lds width=16, 16x16x32 bf16 MFMA, 4x4 acc per wave).

#define DIM 2048
#define NTOT 6144   // 3*DIM, concatenated q|k|v per token
#define DG 128      // per-group dim
#define NG 16       // groups

typedef __bf16 bf16x8 __attribute__((ext_vector_type(8)));
typedef float f32x4 __attribute__((ext_vector_type(4)));
typedef unsigned short u16;
typedef unsigned int u32;

__device__ __forceinline__ u16 f2bf(float f) {
  u32 u = __float_as_uint(f);
  u = (u + 0x7fffu + ((u >> 16) & 1u)) >> 16;  // RNE
  return (u16)u;
}

__device__ __forceinline__ void gload16(const __bf16* g, __bf16* l) {
  // async global->LDS DMA, 16B per lane; LDS dest = wave-uniform base + lane*16
  __builtin_amdgcn_global_load_lds(
      (__attribute__((address_space(1))) void*)(void*)g,
      (__attribute__((address_space(3))) void*)l, 16, 0, 0);
}

__global__ __launch_bounds__(256) void cvt_kernel(const float* __restrict__ src,
                                                  u16* __restrict__ dst, int n4) {
  int i = blockIdx.x * 256 + threadIdx.x;
  if (i >= n4) return;
  float4 f = ((const float4*)src)[i];
  ushort4 o;
  o.x = f2bf(f.x); o.y = f2bf(f.y); o.z = f2bf(f.z); o.w = f2bf(f.w);
  ((ushort4*)dst)[i] = o;
}

__global__ __launch_bounds__(256) void cvtW_kernel(const float* __restrict__ wq,
                                                   const float* __restrict__ wk,
                                                   const float* __restrict__ wv,
                                                   u16* __restrict__ dst, int n4each) {
  int m = blockIdx.y;
  const float* s = (m == 0) ? wq : (m == 1) ? wk : wv;
  int i = blockIdx.x * 256 + threadIdx.x;
  if (i >= n4each) return;
  float4 f = ((const float4*)s)[i];
  ushort4 o;
  o.x = f2bf(f.x); o.y = f2bf(f.y); o.z = f2bf(f.z); o.w = f2bf(f.w);
  ((ushort4*)dst)[(size_t)m * n4each + i] = o;
}

// C[row][bn*128+col] = A[row][:] . W[bn*128+col][:] + bias, stored bf16.
// A: [M][2048] bf16, W: [6144][2048] bf16 (Wq|Wk|Wv rows), C: [M][6144] bf16.
__global__ __launch_bounds__(256) void gemm_qkv(const __bf16* __restrict__ A,
                                                const __bf16* __restrict__ W,
                                                const float* __restrict__ bq,
                                                const float* __restrict__ bk,
                                                const float* __restrict__ bv,
                                                u16* __restrict__ C) {
  __shared__ __bf16 sA[128 * 32];  // 8 KB, row-major [128][32], K contiguous
  __shared__ __bf16 sB[128 * 32];  // 8 KB

  const int tid = threadIdx.x;
  const int lane = tid & 63;
  const int w = tid >> 6;          // wave 0..3
  const int wm = w >> 1, wn = w & 1;
  const int lm = lane & 15, kq = lane >> 4;

  const int bm = blockIdx.x, bn = blockIdx.y;

  // staging: tile has 512 16B-chunks; chunk cid -> row=cid>>2, colchunk=cid&3
  const int cid0 = w * 128 + lane;
  const int cid1 = cid0 + 64;
  const __bf16* pA0 = A + (size_t)(bm * 128 + (cid0 >> 2)) * DIM + (cid0 & 3) * 8;
  const __bf16* pA1 = A + (size_t)(bm * 128 + (cid1 >> 2)) * DIM + (cid1 & 3) * 8;
  const __bf16* pB0 = W + (size_t)(bn * 128 + (cid0 >> 2)) * DIM + (cid0 & 3) * 8;
  const __bf16* pB1 = W + (size_t)(bn * 128 + (cid1 >> 2)) * DIM + (cid1 & 3) * 8;
  __bf16* dA0 = sA + (w * 2 + 0) * 512;   // 64 lanes * 8 elems
  __bf16* dA1 = sA + (w * 2 + 1) * 512;
  __bf16* dB0 = sB + (w * 2 + 0) * 512;
  __bf16* dB1 = sB + (w * 2 + 1) * 512;

  f32x4 acc[4][4];
#pragma unroll
  for (int i = 0; i < 4; ++i)
#pragma unroll
    for (int j = 0; j < 4; ++j) acc[i][j] = (f32x4){0.f, 0.f, 0.f, 0.f};

  // LDS fragment read bases: A[m=lane&15][k=quad*8+j] pattern (16x16x32 layout)
  const __bf16* la = sA + (wm * 64 + lm) * 32 + kq * 8;
  const __bf16* lb = sB + (wn * 64 + lm) * 32 + kq * 8;

  for (int k0 = 0; k0 < DIM; k0 += 32) {
    __syncthreads();               // previous compute done before overwrite
    gload16(pA0, dA0);
    gload16(pA1, dA1);
    gload16(pB0, dB0);
    gload16(pB1, dB1);
    pA0 += 32; pA1 += 32; pB0 += 32; pB1 += 32;
    __syncthreads();               // drains vmcnt -> LDS ready

    bf16x8 a[4], b[4];
#pragma unroll
    for (int i = 0; i < 4; ++i) a[i] = *(const bf16x8*)(la + i * 16 * 32);
#pragma unroll
    for (int j = 0; j < 4; ++j) b[j] = *(const bf16x8*)(lb + j * 16 * 32);
#pragma unroll
    for (int i = 0; i < 4; ++i)
#pragma unroll
      for (int j = 0; j < 4; ++j)
        acc[i][j] = __builtin_amdgcn_mfma_f32_16x16x32_bf16(a[i], b[j], acc[i][j], 0, 0, 0);
  }

  // epilogue: C/D layout col=lane&15, row=(lane>>4)*4+reg (verified m89/m91)
  const int mat = bn >> 4;
  const float* bias = (mat == 0) ? bq : (mat == 1) ? bk : bv;
  const int colb = bn * 128 + wn * 64 + lm;
  const int rowb = bm * 128 + wm * 64 + kq * 4;
#pragma unroll
  for (int i = 0; i < 4; ++i) {
#pragma unroll
    for (int j = 0; j < 4; ++j) {
      const int col = colb + j * 16;
      const float bs = bias[col & (DIM - 1)];
#pragma unroll
      for (int r = 0; r < 4; ++r) {
        const int row = rowb + i * 16 + r;
        C[(size_t)row * NTOT + col] = f2bf(acc[i][j][r] + bs);
      }
    }
  }
}

__device__ __forceinline__ void unpack8(uint4 v, float* f) {
  f[0] = __uint_as_float(v.x << 16);
  f[1] = __uint_as_float(v.x & 0xffff0000u);
  f[2] = __uint_as_float(v.y << 16);
  f[3] = __uint_as_float(v.y & 0xffff0000u);
  f[4] = __uint_as_float(v.z << 16);
  f[5] = __uint_as_float(v.z & 0xffff0000u);
  f[6] = __uint_as_float(v.w << 16);
  f[7] = __uint_as_float(v.w & 0xffff0000u);
}

// One lane per (token, group): scores over 16 heads, thread-local softmax,
// out[g][0:128]. k/v loads are lockstep-identical across a token's 16 lanes
// (coalesced broadcast).
__global__ __launch_bounds__(256) void attn_kernel(const u16* __restrict__ qkv,
                                                   float* __restrict__ out) {
  const int tid = threadIdx.x;
  const int token = blockIdx.x * 16 + (tid >> 4);
  const int g = tid & 15;
  const u16* base = qkv + (size_t)token * NTOT;
  const uint4* qb = (const uint4*)(base + g * DG);
  const uint4* kb = (const uint4*)(base + DIM);
  const uint4* vb = (const uint4*)(base + 2 * DIM);

  float sc[16];
#pragma unroll
  for (int h = 0; h < 16; ++h) sc[h] = 0.f;

  for (int c = 0; c < 16; ++c) {   // 16 chunks of 8 elems over d=128
    uint4 qc = qb[c];
    float qf[8];
    unpack8(qc, qf);
#pragma unroll
    for (int h = 0; h < 16; ++h) {
      uint4 kc = kb[h * 16 + c];
      float kf[8];
      unpack8(kc, kf);
      float s = sc[h];
      s = fmaf(qf[0], kf[0], s);
      s = fmaf(qf[1], kf[1], s);
      s = fmaf(qf[2], kf[2], s);
      s = fmaf(qf[3], kf[3], s);
      s = fmaf(qf[4], kf[4], s);
      s = fmaf(qf[5], kf[5], s);
      s = fmaf(qf[6], kf[6], s);
      s = fmaf(qf[7], kf[7], s);
      sc[h] = s;
    }
  }

  const float scale = 0.08838834764831845f;  // 1/sqrt(128)
  float mx = sc[0] * scale;
#pragma unroll
  for (int h = 1; h < 16; ++h) mx = fmaxf(mx, sc[h] * scale);
  float p[16], sum = 0.f;
#pragma unroll
  for (int h = 0; h < 16; ++h) {
    p[h] = __expf(sc[h] * scale - mx);
    sum += p[h];
  }
  const float inv = 1.f / sum;
#pragma unroll
  for (int h = 0; h < 16; ++h) p[h] *= inv;

  float* ob = out + (size_t)token * DIM + g * DG;
  for (int c = 0; c < 16; ++c) {
    float o[8];
#pragma unroll
    for (int e = 0; e < 8; ++e) o[e] = 0.f;
#pragma unroll
    for (int h = 0; h < 16; ++h) {
      uint4 vc = vb[h * 16 + c];
      float vf[8];
      unpack8(vc, vf);
#pragma unroll
      for (int e = 0; e < 8; ++e) o[e] = fmaf(p[h], vf[e], o[e]);
    }
    float4 o0 = {o[0], o[1], o[2], o[3]};
    float4 o1 = {o[4], o[5], o[6], o[7]};
    ((float4*)ob)[c * 2] = o0;
    ((float4*)ob)[c * 2 + 1] = o1;
  }
}

extern "C" void kernel_launch(void* const* d_in, const int* in_sizes, int n_in,
                              void* d_out, int out_size, void* d_ws, size_t ws_size,
                              hipStream_t stream) {
  const float* x  = (const float*)d_in[0];
  const float* Wq = (const float*)d_in[1];
  const float* bq = (const float*)d_in[2];
  const float* Wk = (const float*)d_in[3];
  const float* bk = (const float*)d_in[4];
  const float* Wv = (const float*)d_in[5];
  const float* bv = (const float*)d_in[6];
  float* out = (float*)d_out;

  const int M = in_sizes[0] / DIM;  // 16384 tokens

  // ws layout: x_bf16 [M*2048] | W_bf16 [3*2048*2048] | qkv_bf16 [M*6144]
  u16* xb  = (u16*)d_ws;
  u16* wb  = xb + (size_t)M * DIM;
  u16* qkv = wb + (size_t)3 * DIM * DIM;

  const int n4x = (M * DIM) / 4;
  cvt_kernel<<<dim3((n4x + 255) / 256), 256, 0, stream>>>(x, xb, n4x);
  const int n4w = (DIM * DIM) / 4;
  cvtW_kernel<<<dim3((n4w + 255) / 256, 3), 256, 0, stream>>>(Wq, Wk, Wv, wb, n4w);

  gemm_qkv<<<dim3(M / 128, 48), 256, 0, stream>>>(
      (const __bf16*)xb, (const __bf16*)wb, bq, bk, bv, qkv);

  attn_kernel<<<dim3(M / 16), 256, 0, stream>>>(qkv, out);
}